// Round 1
// baseline (210.445 us; speedup 1.0000x reference)
//
#include <hip/hip_runtime.h>
#include <hip/hip_bf16.h>

// GroundPlane: RANSAC plane fit + signed distance map.
// B=4, points (B,3,H=384,W=1280) f32; rand_ind (B,125) i32.
// gH=192, N=gH*W=245760 (bottom-half cloud, contiguous tail rows of each channel).
// NOTE reference quirk: ps = tile(gp,(25,1,1)) => ps[m]=gp[m%B] while ws[m], m=b*25+it.
// So fit[b,it] pairs plane ws[b,it] with points of batch pb=(b+it)%4. Replicated here.

constexpr int BN      = 4;
constexpr int H       = 384;
constexpr int W       = 1280;
constexpr int HW      = H * W;          // 491520
constexpr int GH      = 192;            // int(0.5*H)
constexpr int NPTS    = GH * W;         // 245760
constexpr int MAX_IT  = 25;
constexpr int NUM_PTS = 5;
constexpr int TOTAL_P = BN * MAX_IT;    // 100 planes

constexpr int CHUNKS      = 64;                  // blocks per point-batch in k_count
constexpr int PTS_PER_BLK = NPTS / CHUNKS;       // 3840
constexpr int BLOCKS_PER_B = (HW / 4) / 256;     // 480 (k_dist, float4 per thread)

// ---------------- Kernel 1: fit 100 planes (double precision) ----------------
__global__ void k_fit(const float* __restrict__ pts, const int* __restrict__ rind,
                      double* __restrict__ wsd, float* __restrict__ wsf,
                      int* __restrict__ counts) {
    int t = threadIdx.x;
    if (t < TOTAL_P) counts[t] = 0;   // zero inlier counters every call (ws is poisoned)
    if (t >= TOTAL_P) return;
    int b  = t / MAX_IT;
    // gather 5 sampled points: gp[b,n,c] = pts[b*3*HW + c*HW + (H-GH)*W + n]
    const float* base = pts + (size_t)b * 3 * HW + (size_t)(H - GH) * W;
    double Sxx = 0, Sxz = 0, Sx = 0, Szz = 0, Sz = 0, Sxy = 0, Szy = 0, Sy = 0;
    const int* ri = rind + b * (MAX_IT * NUM_PTS) + (t % MAX_IT) * NUM_PTS;
#pragma unroll
    for (int p = 0; p < NUM_PTS; ++p) {
        int n = ri[p];
        double x = (double)base[n];
        double y = (double)base[HW + n];        // VAX=1 -> y is the "B" column
        double z = (double)base[2 * HW + n];
        Sxx += x * x; Sxz += x * z; Sx += x;
        Szz += z * z; Sz += z;
        Sxy += x * y; Szy += z * y; Sy += y;
    }
    // M = AtA + 1e-6 (broadcast add to ALL entries, matching `At@A + 1e-06`)
    const double e = 1e-6;
    double m00 = Sxx + e, m01 = Sxz + e, m02 = Sx + e;
    double m10 = Sxz + e, m11 = Szz + e, m12 = Sz + e;
    double m20 = Sx + e,  m21 = Sz + e,  m22 = (double)NUM_PTS + e;
    double v0 = Sxy, v1 = Szy, v2 = Sy;
    double det = m00 * (m11 * m22 - m12 * m21)
               - m01 * (m10 * m22 - m12 * m20)
               + m02 * (m10 * m21 - m11 * m20);
    double inv = 1.0 / det;
    double d0 = v0  * (m11 * m22 - m12 * m21)
              - m01 * (v1  * m22 - m12 * v2 )
              + m02 * (v1  * m21 - m11 * v2 );
    double d1 = m00 * (v1  * m22 - m12 * v2 )
              - v0  * (m10 * m22 - m12 * m20)
              + m02 * (m10 * v2  - v1  * m20);
    double d2 = m00 * (m11 * v2  - v1  * m21)
              - m01 * (m10 * v2  - v1  * m20)
              + v0  * (m10 * m21 - m11 * m20);
    double w0 = d0 * inv, w1 = d1 * inv, w2 = d2 * inv;
    wsd[t * 3 + 0] = w0; wsd[t * 3 + 1] = w1; wsd[t * 3 + 2] = w2;
    wsf[t * 3 + 0] = (float)w0; wsf[t * 3 + 1] = (float)w1; wsf[t * 3 + 2] = (float)w2;
}

// ------------- Kernel 2: inlier counts, 25 planes per point-batch -------------
__global__ void k_count(const float* __restrict__ pts, const double* __restrict__ wsd,
                        int* __restrict__ counts) {
    __shared__ double sw[MAX_IT][3];
    __shared__ int    scid[MAX_IT];
    int pb    = blockIdx.x / CHUNKS;   // which point-batch this block reads
    int chunk = blockIdx.x % CHUNKS;
    if (threadIdx.x == 0) {
        // planes (b,it) with (b+it)%4 == pb  -> exactly 25 of them
        int s = 0;
        for (int b = 0; b < BN; ++b) {
            int r = ((pb - b) % BN + BN) % BN;
            for (int it = r; it < MAX_IT; it += BN) {
                int pi = b * MAX_IT + it;
                sw[s][0] = wsd[pi * 3 + 0];
                sw[s][1] = wsd[pi * 3 + 1];
                sw[s][2] = wsd[pi * 3 + 2];
                scid[s]  = pi;
                ++s;
            }
        }
    }
    __syncthreads();
    const float* base = pts + (size_t)pb * 3 * HW + (size_t)(H - GH) * W;
    int acc[MAX_IT];
#pragma unroll
    for (int s = 0; s < MAX_IT; ++s) acc[s] = 0;
    int start = chunk * PTS_PER_BLK + threadIdx.x;
    int end   = chunk * PTS_PER_BLK + PTS_PER_BLK;
    for (int n = start; n < end; n += 256) {
        double x = (double)base[n];
        double y = (double)base[HW + n];
        double z = (double)base[2 * HW + n];
#pragma unroll
        for (int s = 0; s < MAX_IT; ++s) {
            double d = x * sw[s][0] + z * sw[s][1] + sw[s][2] - y;
            acc[s] += (fabs(d) < 0.1) ? 1 : 0;
        }
    }
#pragma unroll
    for (int s = 0; s < MAX_IT; ++s) {
        int v = acc[s];
        for (int off = 32; off > 0; off >>= 1) v += __shfl_down(v, off, 64);
        if ((threadIdx.x & 63) == 0) atomicAdd(&counts[scid[s]], v);
    }
}

// ------ Kernel 3: per-batch argmax (redundant, cached) + full dist map -------
__global__ void k_dist(const float* __restrict__ pts, const float* __restrict__ wsf,
                       const int* __restrict__ counts, float* __restrict__ out) {
    __shared__ float sw[3];
    int b   = blockIdx.x / BLOCKS_PER_B;
    int blk = blockIdx.x % BLOCKS_PER_B;
    if (threadIdx.x == 0) {
        int best = 0, bc = counts[b * MAX_IT];
        for (int it = 1; it < MAX_IT; ++it) {
            int c = counts[b * MAX_IT + it];
            if (c > bc) { bc = c; best = it; }   // strict > : first-max, matches argmax
        }
        int pi = b * MAX_IT + best;
        sw[0] = wsf[pi * 3 + 0];
        sw[1] = wsf[pi * 3 + 1];
        sw[2] = wsf[pi * 3 + 2];
        if (blk == 0) {   // best_w output tail: (B,3,1) = 12 floats
            out[(size_t)BN * HW + b * 3 + 0] = sw[0];
            out[(size_t)BN * HW + b * 3 + 1] = sw[1];
            out[(size_t)BN * HW + b * 3 + 2] = sw[2];
        }
    }
    __syncthreads();
    float w0 = sw[0], w1 = sw[1], w2 = sw[2];
    const float4* px = (const float4*)(pts + (size_t)b * 3 * HW);
    const float4* py = px + HW / 4;
    const float4* pz = py + HW / 4;
    int i = blk * 256 + threadIdx.x;   // element in [0, HW/4)
    float4 x = px[i], y = py[i], z = pz[i];
    float4 r;
    r.x = w0 * x.x + w1 * z.x + w2 - y.x;
    r.y = w0 * x.y + w1 * z.y + w2 - y.y;
    r.z = w0 * x.z + w1 * z.z + w2 - y.z;
    r.w = w0 * x.w + w1 * z.w + w2 - y.w;
    ((float4*)(out + (size_t)b * HW))[i] = r;
}

extern "C" void kernel_launch(void* const* d_in, const int* in_sizes, int n_in,
                              void* d_out, int out_size, void* d_ws, size_t ws_size,
                              hipStream_t stream) {
    const float* pts  = (const float*)d_in[0];
    const int*   rind = (const int*)d_in[1];
    float* out = (float*)d_out;

    double* wsd   = (double*)d_ws;                 // 300 doubles
    float*  wsf   = (float*)(wsd + TOTAL_P * 3);   // 300 floats
    int*    cnts  = (int*)(wsf + TOTAL_P * 3);     // 100 ints

    k_fit  <<<1, 128, 0, stream>>>(pts, rind, wsd, wsf, cnts);
    k_count<<<BN * CHUNKS, 256, 0, stream>>>(pts, wsd, cnts);
    k_dist <<<BN * BLOCKS_PER_B, 256, 0, stream>>>(pts, wsf, cnts, out);
}

// Round 2
// 93.164 us; speedup vs baseline: 2.2589x; 2.2589x over previous
//
#include <hip/hip_runtime.h>
#include <hip/hip_bf16.h>

// GroundPlane: RANSAC plane fit + signed distance map.
// B=4, points (B,3,H=384,W=1280) f32; rand_ind (B,125) i32.
// gH=192, N=gH*W=245760 (bottom-half cloud = tail rows of each channel, contiguous).
// Reference quirk: ps = tile(gp,(25,1,1)) => plane m=b*25+it is scored against
// point-batch (b+it)%4 (25 = 1 mod 4). Replicated here.
//
// R2: k_count was 144us due to scratch spill (VGPR capped at 64 by default
// 1024-thread launch-bounds assumption; acc[25] spilled -> 18.7MB WRITE_SIZE).
// Restructured: 5 plane-groups of 5, __launch_bounds__(256), float4 loads,
// registers-resident weights, LDS block reduction -> 1 atomic/plane/block.

constexpr int BN      = 4;
constexpr int H       = 384;
constexpr int W       = 1280;
constexpr int HW      = H * W;          // 491520
constexpr int GH      = 192;            // int(0.5*H)
constexpr int NPTS    = GH * W;         // 245760
constexpr int MAX_IT  = 25;
constexpr int NUM_PTS = 5;
constexpr int TOTAL_P = BN * MAX_IT;    // 100 planes

constexpr int NGRP        = 5;                     // plane-groups per point-batch
constexpr int GSZ         = 5;                     // planes per group
constexpr int CHUNKS      = 30;                    // chunks per (pb,grp)
constexpr int F4_PER_CHUNK = NPTS / 4 / CHUNKS;    // 2048 float4 per chunk
constexpr int ITERS       = F4_PER_CHUNK / 256;    // 8 float4 per thread
constexpr int BLOCKS_PER_B = (HW / 4) / 256;       // 480 (k_dist)

// ---------------- Kernel 1: fit 100 planes (double precision) ----------------
__global__ __launch_bounds__(128) void k_fit(
        const float* __restrict__ pts, const int* __restrict__ rind,
        double* __restrict__ wsd, float* __restrict__ wsf,
        int* __restrict__ counts) {
    int t = threadIdx.x;
    if (t < TOTAL_P) counts[t] = 0;   // zero inlier counters (ws poisoned every call)
    if (t >= TOTAL_P) return;
    int b = t / MAX_IT;
    const float* base = pts + (size_t)b * 3 * HW + (size_t)(H - GH) * W;
    double Sxx = 0, Sxz = 0, Sx = 0, Szz = 0, Sz = 0, Sxy = 0, Szy = 0, Sy = 0;
    const int* ri = rind + b * (MAX_IT * NUM_PTS) + (t % MAX_IT) * NUM_PTS;
#pragma unroll
    for (int p = 0; p < NUM_PTS; ++p) {
        int n = ri[p];
        double x = (double)base[n];
        double y = (double)base[HW + n];        // VAX=1 -> y is the "B" column
        double z = (double)base[2 * HW + n];
        Sxx += x * x; Sxz += x * z; Sx += x;
        Szz += z * z; Sz += z;
        Sxy += x * y; Szy += z * y; Sy += y;
    }
    const double e = 1e-6;
    double m00 = Sxx + e, m01 = Sxz + e, m02 = Sx + e;
    double m10 = Sxz + e, m11 = Szz + e, m12 = Sz + e;
    double m20 = Sx + e,  m21 = Sz + e,  m22 = (double)NUM_PTS + e;
    double v0 = Sxy, v1 = Szy, v2 = Sy;
    double det = m00 * (m11 * m22 - m12 * m21)
               - m01 * (m10 * m22 - m12 * m20)
               + m02 * (m10 * m21 - m11 * m20);
    double inv = 1.0 / det;
    double d0 = v0  * (m11 * m22 - m12 * m21)
              - m01 * (v1  * m22 - m12 * v2 )
              + m02 * (v1  * m21 - m11 * v2 );
    double d1 = m00 * (v1  * m22 - m12 * v2 )
              - v0  * (m10 * m22 - m12 * m20)
              + m02 * (m10 * v2  - v1  * m20);
    double d2 = m00 * (m11 * v2  - v1  * m21)
              - m01 * (m10 * v2  - v1  * m20)
              + v0  * (m10 * m21 - m11 * m20);
    double w0 = d0 * inv, w1 = d1 * inv, w2 = d2 * inv;
    wsd[t * 3 + 0] = w0; wsd[t * 3 + 1] = w1; wsd[t * 3 + 2] = w2;
    wsf[t * 3 + 0] = (float)w0; wsf[t * 3 + 1] = (float)w1; wsf[t * 3 + 2] = (float)w2;
}

// ------- Kernel 2: inlier counts; 5 planes per block, float4 point loads ------
__global__ __launch_bounds__(256) void k_count(
        const float* __restrict__ pts, const double* __restrict__ wsd,
        int* __restrict__ counts) {
    __shared__ double swt[GSZ][3];
    __shared__ int    spid[GSZ];
    __shared__ int    sacc[GSZ];
    // grid: grp fastest, then pb, then chunk (same-chunk blocks adjacent -> L2 reuse)
    int grp   = blockIdx.x % NGRP;
    int pb    = (blockIdx.x / NGRP) % BN;
    int chunk = blockIdx.x / (NGRP * BN);
    int tid   = threadIdx.x;
    if (tid < GSZ) sacc[tid] = 0;
    if (tid == 0) {
        // enumerate the 25 planes (b,it) with (b+it)%4==pb; stage group grp's 5
        int s = 0, lo = grp * GSZ;
        for (int b = 0; b < BN; ++b) {
            int r = ((pb - b) % BN + BN) % BN;
            for (int it = r; it < MAX_IT; it += BN) {
                if (s >= lo && s < lo + GSZ) {
                    int pi = b * MAX_IT + it;
                    int j = s - lo;
                    swt[j][0] = wsd[pi * 3 + 0];
                    swt[j][1] = wsd[pi * 3 + 1];
                    swt[j][2] = wsd[pi * 3 + 2];
                    spid[j]   = pi;
                }
                ++s;
            }
        }
    }
    __syncthreads();
    // hoist weights to registers (15 f64)
    double wa0 = swt[0][0], wa1 = swt[0][1], wa2 = swt[0][2];
    double wb0 = swt[1][0], wb1 = swt[1][1], wb2 = swt[1][2];
    double wc0 = swt[2][0], wc1 = swt[2][1], wc2 = swt[2][2];
    double wd0 = swt[3][0], wd1 = swt[3][1], wd2 = swt[3][2];
    double we0 = swt[4][0], we1 = swt[4][1], we2 = swt[4][2];

    const float* base = pts + (size_t)pb * 3 * HW + (size_t)(H - GH) * W;
    const float4* px = (const float4*)base;
    const float4* py = (const float4*)(base + HW);
    const float4* pz = (const float4*)(base + 2 * HW);

    int a0 = 0, a1 = 0, a2 = 0, a3 = 0, a4 = 0;
#pragma unroll
    for (int it = 0; it < ITERS; ++it) {
        int f = chunk * F4_PER_CHUNK + it * 256 + tid;
        float4 x4 = px[f], y4 = py[f], z4 = pz[f];
#pragma unroll
        for (int e = 0; e < 4; ++e) {
            double x = (double)((const float*)&x4)[e];
            double y = (double)((const float*)&y4)[e];
            double z = (double)((const float*)&z4)[e];
            double nb = -y;   // d = x*w0 + z*w1 + (w2 - y)
            a0 += (fabs(fma(x, wa0, fma(z, wa1, wa2 + nb))) < 0.1) ? 1 : 0;
            a1 += (fabs(fma(x, wb0, fma(z, wb1, wb2 + nb))) < 0.1) ? 1 : 0;
            a2 += (fabs(fma(x, wc0, fma(z, wc1, wc2 + nb))) < 0.1) ? 1 : 0;
            a3 += (fabs(fma(x, wd0, fma(z, wd1, wd2 + nb))) < 0.1) ? 1 : 0;
            a4 += (fabs(fma(x, we0, fma(z, we1, we2 + nb))) < 0.1) ? 1 : 0;
        }
    }
    // wave reduce then block reduce in LDS
    int vals[GSZ] = {a0, a1, a2, a3, a4};
#pragma unroll
    for (int j = 0; j < GSZ; ++j) {
        int v = vals[j];
        for (int off = 32; off > 0; off >>= 1) v += __shfl_down(v, off, 64);
        if ((tid & 63) == 0) atomicAdd(&sacc[j], v);
    }
    __syncthreads();
    if (tid < GSZ) atomicAdd(&counts[spid[tid]], sacc[tid]);
}

// ------ Kernel 3: per-batch argmax (redundant, cached) + full dist map -------
__global__ __launch_bounds__(256) void k_dist(
        const float* __restrict__ pts, const float* __restrict__ wsf,
        const int* __restrict__ counts, float* __restrict__ out) {
    __shared__ float sw[3];
    int b   = blockIdx.x / BLOCKS_PER_B;
    int blk = blockIdx.x % BLOCKS_PER_B;
    if (threadIdx.x == 0) {
        int best = 0, bc = counts[b * MAX_IT];
        for (int it = 1; it < MAX_IT; ++it) {
            int c = counts[b * MAX_IT + it];
            if (c > bc) { bc = c; best = it; }   // strict > : first-max == np argmax
        }
        int pi = b * MAX_IT + best;
        sw[0] = wsf[pi * 3 + 0];
        sw[1] = wsf[pi * 3 + 1];
        sw[2] = wsf[pi * 3 + 2];
        if (blk == 0) {   // best_w tail: (B,3,1) = 12 floats
            out[(size_t)BN * HW + b * 3 + 0] = sw[0];
            out[(size_t)BN * HW + b * 3 + 1] = sw[1];
            out[(size_t)BN * HW + b * 3 + 2] = sw[2];
        }
    }
    __syncthreads();
    float w0 = sw[0], w1 = sw[1], w2 = sw[2];
    const float4* px = (const float4*)(pts + (size_t)b * 3 * HW);
    const float4* py = px + HW / 4;
    const float4* pz = py + HW / 4;
    int i = blk * 256 + threadIdx.x;   // element in [0, HW/4)
    float4 x = px[i], y = py[i], z = pz[i];
    float4 r;
    r.x = w0 * x.x + w1 * z.x + w2 - y.x;
    r.y = w0 * x.y + w1 * z.y + w2 - y.y;
    r.z = w0 * x.z + w1 * z.z + w2 - y.z;
    r.w = w0 * x.w + w1 * z.w + w2 - y.w;
    ((float4*)(out + (size_t)b * HW))[i] = r;
}

extern "C" void kernel_launch(void* const* d_in, const int* in_sizes, int n_in,
                              void* d_out, int out_size, void* d_ws, size_t ws_size,
                              hipStream_t stream) {
    const float* pts  = (const float*)d_in[0];
    const int*   rind = (const int*)d_in[1];
    float* out = (float*)d_out;

    double* wsd  = (double*)d_ws;                 // 300 doubles
    float*  wsf  = (float*)(wsd + TOTAL_P * 3);   // 300 floats
    int*    cnts = (int*)(wsf + TOTAL_P * 3);     // 100 ints

    k_fit  <<<1, 128, 0, stream>>>(pts, rind, wsd, wsf, cnts);
    k_count<<<NGRP * BN * CHUNKS, 256, 0, stream>>>(pts, wsd, cnts);
    k_dist <<<BN * BLOCKS_PER_B, 256, 0, stream>>>(pts, wsf, cnts, out);
}

// Round 4
// 87.018 us; speedup vs baseline: 2.4184x; 1.0706x over previous
//
#include <hip/hip_runtime.h>
#include <hip/hip_bf16.h>

// GroundPlane: RANSAC plane fit + signed distance map.
// B=4, points (B,3,H=384,W=1280) f32; rand_ind (B,125) i32.
// gH=192, N=gH*W=245760 (bottom-half cloud = tail rows of each channel, contiguous).
// Reference quirk: ps = tile(gp,(25,1,1)) => plane m=b*25+it is scored against
// point-batch (b+it)%4 (25 = 1 mod 4). Replicated here.
//
// R2: fixed scratch spill (VGPR cap) -> 210us to 93us.
// R3: harness's 256MiB 0xAA poison fill (43us) sits inside the timed window
// -> ~50us floor. Fold k_fit into k_count (threads 0..4 of each block
// redundantly fit the block's 5 planes; gathers are L2-hot, f64 math is
// bit-identical across blocks), zero counts via capturable hipMemsetAsync,
// CHUNKS 30->60 for latency hiding. R3 bench was an infra flake; resubmit.

constexpr int BN      = 4;
constexpr int H       = 384;
constexpr int W       = 1280;
constexpr int HW      = H * W;          // 491520
constexpr int GH      = 192;            // int(0.5*H)
constexpr int NPTS    = GH * W;         // 245760
constexpr int MAX_IT  = 25;
constexpr int NUM_PTS = 5;
constexpr int TOTAL_P = BN * MAX_IT;    // 100 planes

constexpr int NGRP         = 5;                    // plane-groups per point-batch
constexpr int GSZ          = 5;                    // planes per group
constexpr int CHUNKS       = 60;                   // chunks per (pb,grp)
constexpr int F4_PER_CHUNK = NPTS / 4 / CHUNKS;    // 1024 float4 per chunk
constexpr int ITERS        = F4_PER_CHUNK / 256;   // 4 float4 per thread
constexpr int BLOCKS_PER_B = (HW / 4) / 256;       // 480 (k_dist)

// ---- Kernel 1: fit (redundant per block, threads 0..4) + inlier counts ----
__global__ __launch_bounds__(256) void k_count(
        const float* __restrict__ pts, const int* __restrict__ rind,
        float* __restrict__ wsf, int* __restrict__ counts) {
    __shared__ double swt[GSZ][3];
    __shared__ int    spid[GSZ];
    __shared__ int    sacc[GSZ];
    // grid: grp fastest, then pb, then chunk
    int grp   = blockIdx.x % NGRP;
    int pb    = (blockIdx.x / NGRP) % BN;
    int chunk = blockIdx.x / (NGRP * BN);
    int tid   = threadIdx.x;
    if (tid < GSZ) {
        sacc[tid] = 0;
        // enumerate planes (b,it) with (b+it)%4==pb; pick the (grp*GSZ+tid)-th
        int target = grp * GSZ + tid;
        int s = 0, pi = 0;
        for (int b = 0; b < BN; ++b) {
            int r = ((pb - b) % BN + BN) % BN;
            for (int it = r; it < MAX_IT; it += BN) {
                if (s == target) pi = b * MAX_IT + it;
                ++s;
            }
        }
        spid[tid] = pi;
        // --- fit plane pi from batch (pi/25)'s sampled points, f64 Cramer ---
        int fb = pi / MAX_IT, fit_it = pi % MAX_IT;
        const float* base = pts + (size_t)fb * 3 * HW + (size_t)(H - GH) * W;
        const int* ri = rind + fb * (MAX_IT * NUM_PTS) + fit_it * NUM_PTS;
        double Sxx = 0, Sxz = 0, Sx = 0, Szz = 0, Sz = 0, Sxy = 0, Szy = 0, Sy = 0;
#pragma unroll
        for (int p = 0; p < NUM_PTS; ++p) {
            int n = ri[p];
            double x = (double)base[n];
            double y = (double)base[HW + n];        // VAX=1 -> y is the "B" column
            double z = (double)base[2 * HW + n];
            Sxx += x * x; Sxz += x * z; Sx += x;
            Szz += z * z; Sz += z;
            Sxy += x * y; Szy += z * y; Sy += y;
        }
        const double e = 1e-6;   // AtA + 1e-6 broadcasts onto ALL nine entries
        double m00 = Sxx + e, m01 = Sxz + e, m02 = Sx + e;
        double m10 = Sxz + e, m11 = Szz + e, m12 = Sz + e;
        double m20 = Sx + e,  m21 = Sz + e,  m22 = (double)NUM_PTS + e;
        double v0 = Sxy, v1 = Szy, v2 = Sy;
        double det = m00 * (m11 * m22 - m12 * m21)
                   - m01 * (m10 * m22 - m12 * m20)
                   + m02 * (m10 * m21 - m11 * m20);
        double inv = 1.0 / det;
        double d0 = v0  * (m11 * m22 - m12 * m21)
                  - m01 * (v1  * m22 - m12 * v2 )
                  + m02 * (v1  * m21 - m11 * v2 );
        double d1 = m00 * (v1  * m22 - m12 * v2 )
                  - v0  * (m10 * m22 - m12 * m20)
                  + m02 * (m10 * v2  - v1  * m20);
        double d2 = m00 * (m11 * v2  - v1  * m21)
                  - m01 * (m10 * v2  - v1  * m20)
                  + v0  * (m10 * m21 - m11 * m20);
        double w0 = d0 * inv, w1 = d1 * inv, w2 = d2 * inv;
        swt[tid][0] = w0; swt[tid][1] = w1; swt[tid][2] = w2;
        if (chunk == 0) {   // publish f32 weights for k_dist (20 blocks cover all 100)
            wsf[pi * 3 + 0] = (float)w0;
            wsf[pi * 3 + 1] = (float)w1;
            wsf[pi * 3 + 2] = (float)w2;
        }
    }
    __syncthreads();
    // hoist weights to registers (15 f64)
    double wa0 = swt[0][0], wa1 = swt[0][1], wa2 = swt[0][2];
    double wb0 = swt[1][0], wb1 = swt[1][1], wb2 = swt[1][2];
    double wc0 = swt[2][0], wc1 = swt[2][1], wc2 = swt[2][2];
    double wd0 = swt[3][0], wd1 = swt[3][1], wd2 = swt[3][2];
    double we0 = swt[4][0], we1 = swt[4][1], we2 = swt[4][2];

    const float* base = pts + (size_t)pb * 3 * HW + (size_t)(H - GH) * W;
    const float4* px = (const float4*)base;
    const float4* py = (const float4*)(base + HW);
    const float4* pz = (const float4*)(base + 2 * HW);

    int a0 = 0, a1 = 0, a2 = 0, a3 = 0, a4 = 0;
#pragma unroll
    for (int it = 0; it < ITERS; ++it) {
        int f = chunk * F4_PER_CHUNK + it * 256 + tid;
        float4 x4 = px[f], y4 = py[f], z4 = pz[f];
#pragma unroll
        for (int e = 0; e < 4; ++e) {
            double x = (double)((const float*)&x4)[e];
            double y = (double)((const float*)&y4)[e];
            double z = (double)((const float*)&z4)[e];
            double nb = -y;   // d = x*w0 + z*w1 + (w2 - y)
            a0 += (fabs(fma(x, wa0, fma(z, wa1, wa2 + nb))) < 0.1) ? 1 : 0;
            a1 += (fabs(fma(x, wb0, fma(z, wb1, wb2 + nb))) < 0.1) ? 1 : 0;
            a2 += (fabs(fma(x, wc0, fma(z, wc1, wc2 + nb))) < 0.1) ? 1 : 0;
            a3 += (fabs(fma(x, wd0, fma(z, wd1, wd2 + nb))) < 0.1) ? 1 : 0;
            a4 += (fabs(fma(x, we0, fma(z, we1, we2 + nb))) < 0.1) ? 1 : 0;
        }
    }
    // wave reduce then block reduce in LDS, 1 global atomic per plane per block
    int vals[GSZ] = {a0, a1, a2, a3, a4};
#pragma unroll
    for (int j = 0; j < GSZ; ++j) {
        int v = vals[j];
        for (int off = 32; off > 0; off >>= 1) v += __shfl_down(v, off, 64);
        if ((tid & 63) == 0) atomicAdd(&sacc[j], v);
    }
    __syncthreads();
    if (tid < GSZ) atomicAdd(&counts[spid[tid]], sacc[tid]);
}

// ------ Kernel 2: per-batch argmax (redundant, cached) + full dist map -------
__global__ __launch_bounds__(256) void k_dist(
        const float* __restrict__ pts, const float* __restrict__ wsf,
        const int* __restrict__ counts, float* __restrict__ out) {
    __shared__ float sw[3];
    int b   = blockIdx.x / BLOCKS_PER_B;
    int blk = blockIdx.x % BLOCKS_PER_B;
    if (threadIdx.x == 0) {
        int best = 0, bc = counts[b * MAX_IT];
        for (int it = 1; it < MAX_IT; ++it) {
            int c = counts[b * MAX_IT + it];
            if (c > bc) { bc = c; best = it; }   // strict > : first-max == np argmax
        }
        int pi = b * MAX_IT + best;
        sw[0] = wsf[pi * 3 + 0];
        sw[1] = wsf[pi * 3 + 1];
        sw[2] = wsf[pi * 3 + 2];
        if (blk == 0) {   // best_w tail: (B,3,1) = 12 floats
            out[(size_t)BN * HW + b * 3 + 0] = sw[0];
            out[(size_t)BN * HW + b * 3 + 1] = sw[1];
            out[(size_t)BN * HW + b * 3 + 2] = sw[2];
        }
    }
    __syncthreads();
    float w0 = sw[0], w1 = sw[1], w2 = sw[2];
    const float4* px = (const float4*)(pts + (size_t)b * 3 * HW);
    const float4* py = px + HW / 4;
    const float4* pz = py + HW / 4;
    int i = blk * 256 + threadIdx.x;   // element in [0, HW/4)
    float4 x = px[i], y = py[i], z = pz[i];
    float4 r;
    r.x = w0 * x.x + w1 * z.x + w2 - y.x;
    r.y = w0 * x.y + w1 * z.y + w2 - y.y;
    r.z = w0 * x.z + w1 * z.z + w2 - y.z;
    r.w = w0 * x.w + w1 * z.w + w2 - y.w;
    ((float4*)(out + (size_t)b * HW))[i] = r;
}

extern "C" void kernel_launch(void* const* d_in, const int* in_sizes, int n_in,
                              void* d_out, int out_size, void* d_ws, size_t ws_size,
                              hipStream_t stream) {
    const float* pts  = (const float*)d_in[0];
    const int*   rind = (const int*)d_in[1];
    float* out = (float*)d_out;

    float* wsf  = (float*)d_ws;                   // 300 floats
    int*   cnts = (int*)(wsf + TOTAL_P * 3);      // 100 ints

    hipMemsetAsync(cnts, 0, TOTAL_P * sizeof(int), stream);  // capturable memset node
    k_count<<<NGRP * BN * CHUNKS, 256, 0, stream>>>(pts, rind, wsf, cnts);
    k_dist <<<BN * BLOCKS_PER_B, 256, 0, stream>>>(pts, wsf, cnts, out);
}

// Round 5
// 86.101 us; speedup vs baseline: 2.4442x; 1.0107x over previous
//
#include <hip/hip_runtime.h>
#include <hip/hip_bf16.h>

// GroundPlane: RANSAC plane fit + signed distance map.
// B=4, points (B,3,H=384,W=1280) f32; rand_ind (B,125) i32.
// gH=192, N=gH*W=245760 (bottom-half cloud = tail rows of each channel, contiguous).
// Reference quirk: ps = tile(gp,(25,1,1)) => plane m=b*25+it is scored against
// point-batch (b+it)%4 (25 = 1 mod 4). Replicated here.
//
// R2: fixed scratch spill -> 210us to 93us.  R4: folded fit into k_count -> 87us.
// R5: profile shows the floor is the harness's 256MiB ws poison fill (44.7us
// @75% HBM) + restore nodes; our controllable fat is node count / dependency
// chain. Eliminate the cnts-memset node and all global atomics: k_count writes
// race-free per-(plane,chunk) partial counts (each slot written exactly once,
// so no zero-init needed); k_dist reduces the 25x60 L2-hot partials per block.
// 2 kernel nodes total, no memset node.

constexpr int BN      = 4;
constexpr int H       = 384;
constexpr int W       = 1280;
constexpr int HW      = H * W;          // 491520
constexpr int GH      = 192;            // int(0.5*H)
constexpr int NPTS    = GH * W;         // 245760
constexpr int MAX_IT  = 25;
constexpr int NUM_PTS = 5;
constexpr int TOTAL_P = BN * MAX_IT;    // 100 planes

constexpr int NGRP         = 5;                    // plane-groups per point-batch
constexpr int GSZ          = 5;                    // planes per group
constexpr int CHUNKS       = 60;                   // chunks per (pb,grp)
constexpr int PSTRIDE      = 64;                   // partial-count row stride (pad)
constexpr int F4_PER_CHUNK = NPTS / 4 / CHUNKS;    // 1024 float4 per chunk
constexpr int ITERS        = F4_PER_CHUNK / 256;   // 4 float4 per thread
constexpr int BLOCKS_PER_B = (HW / 4) / 256;       // 480 (k_dist)

// ---- Kernel 1: fit (redundant per block, threads 0..4) + partial counts ----
__global__ __launch_bounds__(256) void k_count(
        const float* __restrict__ pts, const int* __restrict__ rind,
        float* __restrict__ wsf, int* __restrict__ partial) {
    __shared__ double swt[GSZ][3];
    __shared__ int    spid[GSZ];
    __shared__ int    sacc[GSZ];
    // grid: grp fastest, then pb, then chunk
    int grp   = blockIdx.x % NGRP;
    int pb    = (blockIdx.x / NGRP) % BN;
    int chunk = blockIdx.x / (NGRP * BN);
    int tid   = threadIdx.x;
    if (tid < GSZ) {
        sacc[tid] = 0;
        // enumerate planes (b,it) with (b+it)%4==pb; pick the (grp*GSZ+tid)-th
        int target = grp * GSZ + tid;
        int s = 0, pi = 0;
        for (int b = 0; b < BN; ++b) {
            int r = ((pb - b) % BN + BN) % BN;
            for (int it = r; it < MAX_IT; it += BN) {
                if (s == target) pi = b * MAX_IT + it;
                ++s;
            }
        }
        spid[tid] = pi;
        // --- fit plane pi from batch (pi/25)'s sampled points, f64 Cramer ---
        int fb = pi / MAX_IT, fit_it = pi % MAX_IT;
        const float* base = pts + (size_t)fb * 3 * HW + (size_t)(H - GH) * W;
        const int* ri = rind + fb * (MAX_IT * NUM_PTS) + fit_it * NUM_PTS;
        double Sxx = 0, Sxz = 0, Sx = 0, Szz = 0, Sz = 0, Sxy = 0, Szy = 0, Sy = 0;
#pragma unroll
        for (int p = 0; p < NUM_PTS; ++p) {
            int n = ri[p];
            double x = (double)base[n];
            double y = (double)base[HW + n];        // VAX=1 -> y is the "B" column
            double z = (double)base[2 * HW + n];
            Sxx += x * x; Sxz += x * z; Sx += x;
            Szz += z * z; Sz += z;
            Sxy += x * y; Szy += z * y; Sy += y;
        }
        const double e = 1e-6;   // AtA + 1e-6 broadcasts onto ALL nine entries
        double m00 = Sxx + e, m01 = Sxz + e, m02 = Sx + e;
        double m10 = Sxz + e, m11 = Szz + e, m12 = Sz + e;
        double m20 = Sx + e,  m21 = Sz + e,  m22 = (double)NUM_PTS + e;
        double v0 = Sxy, v1 = Szy, v2 = Sy;
        double det = m00 * (m11 * m22 - m12 * m21)
                   - m01 * (m10 * m22 - m12 * m20)
                   + m02 * (m10 * m21 - m11 * m20);
        double inv = 1.0 / det;
        double d0 = v0  * (m11 * m22 - m12 * m21)
                  - m01 * (v1  * m22 - m12 * v2 )
                  + m02 * (v1  * m21 - m11 * v2 );
        double d1 = m00 * (v1  * m22 - m12 * v2 )
                  - v0  * (m10 * m22 - m12 * m20)
                  + m02 * (m10 * v2  - v1  * m20);
        double d2 = m00 * (m11 * v2  - v1  * m21)
                  - m01 * (m10 * v2  - v1  * m20)
                  + v0  * (m10 * m21 - m11 * m20);
        double w0 = d0 * inv, w1 = d1 * inv, w2 = d2 * inv;
        swt[tid][0] = w0; swt[tid][1] = w1; swt[tid][2] = w2;
        if (chunk == 0) {   // publish f32 weights for k_dist (20 blocks cover all 100)
            wsf[pi * 3 + 0] = (float)w0;
            wsf[pi * 3 + 1] = (float)w1;
            wsf[pi * 3 + 2] = (float)w2;
        }
    }
    __syncthreads();
    // hoist weights to registers (15 f64)
    double wa0 = swt[0][0], wa1 = swt[0][1], wa2 = swt[0][2];
    double wb0 = swt[1][0], wb1 = swt[1][1], wb2 = swt[1][2];
    double wc0 = swt[2][0], wc1 = swt[2][1], wc2 = swt[2][2];
    double wd0 = swt[3][0], wd1 = swt[3][1], wd2 = swt[3][2];
    double we0 = swt[4][0], we1 = swt[4][1], we2 = swt[4][2];

    const float* base = pts + (size_t)pb * 3 * HW + (size_t)(H - GH) * W;
    const float4* px = (const float4*)base;
    const float4* py = (const float4*)(base + HW);
    const float4* pz = (const float4*)(base + 2 * HW);

    int a0 = 0, a1 = 0, a2 = 0, a3 = 0, a4 = 0;
#pragma unroll
    for (int it = 0; it < ITERS; ++it) {
        int f = chunk * F4_PER_CHUNK + it * 256 + tid;
        float4 x4 = px[f], y4 = py[f], z4 = pz[f];
#pragma unroll
        for (int e = 0; e < 4; ++e) {
            double x = (double)((const float*)&x4)[e];
            double y = (double)((const float*)&y4)[e];
            double z = (double)((const float*)&z4)[e];
            double nb = -y;   // d = x*w0 + z*w1 + (w2 - y)
            a0 += (fabs(fma(x, wa0, fma(z, wa1, wa2 + nb))) < 0.1) ? 1 : 0;
            a1 += (fabs(fma(x, wb0, fma(z, wb1, wb2 + nb))) < 0.1) ? 1 : 0;
            a2 += (fabs(fma(x, wc0, fma(z, wc1, wc2 + nb))) < 0.1) ? 1 : 0;
            a3 += (fabs(fma(x, wd0, fma(z, wd1, wd2 + nb))) < 0.1) ? 1 : 0;
            a4 += (fabs(fma(x, we0, fma(z, we1, we2 + nb))) < 0.1) ? 1 : 0;
        }
    }
    // wave reduce -> LDS block reduce -> ONE plain store per plane per block
    // (partial[pi][chunk] is written by exactly one block: race-free, no init)
    int vals[GSZ] = {a0, a1, a2, a3, a4};
#pragma unroll
    for (int j = 0; j < GSZ; ++j) {
        int v = vals[j];
        for (int off = 32; off > 0; off >>= 1) v += __shfl_down(v, off, 64);
        if ((tid & 63) == 0) atomicAdd(&sacc[j], v);
    }
    __syncthreads();
    if (tid < GSZ) partial[spid[tid] * PSTRIDE + chunk] = sacc[tid];
}

// -- Kernel 2: per-batch partial-sum + argmax (redundant, L2-hot) + dist map --
__global__ __launch_bounds__(256) void k_dist(
        const float* __restrict__ pts, const float* __restrict__ wsf,
        const int* __restrict__ partial, float* __restrict__ out) {
    __shared__ int   scnt[MAX_IT];
    __shared__ float sw[3];
    int b   = blockIdx.x / BLOCKS_PER_B;
    int blk = blockIdx.x % BLOCKS_PER_B;
    int tid = threadIdx.x;
    if (tid < MAX_IT) {   // thread t sums plane (b,t)'s 60 chunk-partials
        const int* p = partial + (b * MAX_IT + tid) * PSTRIDE;
        int s = 0;
#pragma unroll
        for (int c = 0; c < CHUNKS; ++c) s += p[c];
        scnt[tid] = s;
    }
    __syncthreads();
    if (tid == 0) {
        int best = 0, bc = scnt[0];
        for (int it = 1; it < MAX_IT; ++it) {
            int c = scnt[it];
            if (c > bc) { bc = c; best = it; }   // strict > : first-max == np argmax
        }
        int pi = b * MAX_IT + best;
        sw[0] = wsf[pi * 3 + 0];
        sw[1] = wsf[pi * 3 + 1];
        sw[2] = wsf[pi * 3 + 2];
        if (blk == 0) {   // best_w tail: (B,3,1) = 12 floats
            out[(size_t)BN * HW + b * 3 + 0] = sw[0];
            out[(size_t)BN * HW + b * 3 + 1] = sw[1];
            out[(size_t)BN * HW + b * 3 + 2] = sw[2];
        }
    }
    __syncthreads();
    float w0 = sw[0], w1 = sw[1], w2 = sw[2];
    const float4* px = (const float4*)(pts + (size_t)b * 3 * HW);
    const float4* py = px + HW / 4;
    const float4* pz = py + HW / 4;
    int i = blk * 256 + tid;   // element in [0, HW/4)
    float4 x = px[i], y = py[i], z = pz[i];
    float4 r;
    r.x = w0 * x.x + w1 * z.x + w2 - y.x;
    r.y = w0 * x.y + w1 * z.y + w2 - y.y;
    r.z = w0 * x.z + w1 * z.z + w2 - y.z;
    r.w = w0 * x.w + w1 * z.w + w2 - y.w;
    ((float4*)(out + (size_t)b * HW))[i] = r;
}

extern "C" void kernel_launch(void* const* d_in, const int* in_sizes, int n_in,
                              void* d_out, int out_size, void* d_ws, size_t ws_size,
                              hipStream_t stream) {
    const float* pts  = (const float*)d_in[0];
    const int*   rind = (const int*)d_in[1];
    float* out = (float*)d_out;

    float* wsf     = (float*)d_ws;                  // 300 floats
    int*   partial = (int*)(wsf + TOTAL_P * 3 + 4); // 100*64 ints (each slot
                                                    // written before read; no init)

    k_count<<<NGRP * BN * CHUNKS, 256, 0, stream>>>(pts, rind, wsf, partial);
    k_dist <<<BN * BLOCKS_PER_B, 256, 0, stream>>>(pts, wsf, partial, out);
}